// Round 23
// baseline (749.912 us; speedup 1.0000x reference)
//
#include <hip/hip_runtime.h>
#include <math.h>

// FrequencyAttention mega-kernel (R21): all 8 stages of R18 fused into ONE
// plain kernel with a hand-rolled device-scope grid barrier (cooperative
// launch is rejected under graph capture -- R20 lesson). Stage bodies are
// byte-identical to the R18/R19-verified versions.
// Co-residency: 512 blocks, 32KB LDS/block (5/CU cap), launch_bounds(256,2)
// -> 2 blocks/CU needed; 512 = 2*256 exactly.

#define PB_STRIDE 2097152   // floats per P_B slice (2^21)
#define NBLK 512

typedef __bf16 bf16x8 __attribute__((ext_vector_type(8)));
typedef float  f32x4  __attribute__((ext_vector_type(4)));

__device__ __forceinline__ unsigned short f2bf(float x) {
    unsigned u = __builtin_bit_cast(unsigned, x);
    u = (u + 0x7fffu + ((u >> 16) & 1u)) >> 16;   // RTN-even
    return (unsigned short)u;
}
__device__ __forceinline__ float bf2f(unsigned short h) {
    return __builtin_bit_cast(float, ((unsigned)h) << 16);
}
__device__ __forceinline__ void split2(float x, unsigned short& h, unsigned short& l) {
    h = f2bf(x);
    l = f2bf(x - bf2f(h));
}
__device__ __forceinline__ void splitst(const float4& a0, const float4& a1,
                                        unsigned short* dsth, unsigned short* dstl) {
    float v[8] = {a0.x, a0.y, a0.z, a0.w, a1.x, a1.y, a1.z, a1.w};
    bf16x8 hv, lv;
#pragma unroll
    for (int j = 0; j < 8; j++) {
        unsigned short h, l; split2(v[j], h, l);
        hv[j] = __builtin_bit_cast(__bf16, h);
        lv[j] = __builtin_bit_cast(__bf16, l);
    }
    *reinterpret_cast<bf16x8*>(dsth) = hv;
    *reinterpret_cast<bf16x8*>(dstl) = lv;
}
__device__ __forceinline__ void gload16(const void* g, void* l) {
    __builtin_amdgcn_global_load_lds(
        (const __attribute__((address_space(1))) unsigned int*)g,
        (__attribute__((address_space(3))) unsigned int*)l,
        16, 0, 0);
}

// ---- device-scope grid barrier (sense via generation counter) ---------------
__device__ __forceinline__ void gbar(unsigned* cnt, unsigned* gen) {
    __syncthreads();
    if (threadIdx.x == 0) {
        __threadfence();   // agent-scope release: flush this XCD's L2 writes
        unsigned g = __hip_atomic_load(gen, __ATOMIC_ACQUIRE, __HIP_MEMORY_SCOPE_AGENT);
        unsigned a = __hip_atomic_fetch_add(cnt, 1u, __ATOMIC_ACQ_REL, __HIP_MEMORY_SCOPE_AGENT);
        if (a == NBLK - 1u) {
            __hip_atomic_store(cnt, 0u, __ATOMIC_RELAXED, __HIP_MEMORY_SCOPE_AGENT);
            __hip_atomic_fetch_add(gen, 1u, __ATOMIC_RELEASE, __HIP_MEMORY_SCOPE_AGENT);
        } else {
            while (__hip_atomic_load(gen, __ATOMIC_ACQUIRE, __HIP_MEMORY_SCOPE_AGENT) == g)
                __builtin_amdgcn_s_sleep(8);
        }
        __threadfence();   // agent-scope acquire: invalidate stale caches
    }
    __syncthreads();
}

struct MegaArgs {
    const float *query, *w_qkv, *b_qkv, *w_out, *b_out, *fq, *fk, *fv;
    float* out;
    unsigned short *qTh, *qTl, *TWFh, *TWFl, *TWIh, *TWIl;
    unsigned short *TWQh, *TWQl, *OVWh, *OVWl, *POVh, *POVl;
    float *P_A, *P_C, *P_B;
    unsigned* bar;
};

// ---- prep job (bid in [0,1280)) ---------------------------------------------
__device__ void prep_dev(int bid, unsigned short* smem, const MegaArgs& a) {
    int tid = threadIdx.x;
    if (bid < 256) {                       // twiddles
        int idx = bid * 256 + tid;
        int f = idx >> 10, s = idx & 1023;
        float th = (float)((f * s) & 1023) * (6.283185307179586f / 1024.0f);
        float sn, c;
        sincosf(th, &sn, &c);
        unsigned short ch, cl, sh, sl;
        split2(c, ch, cl); split2(sn, sh, sl);
        a.TWFh[(2 * f) * 1024 + s] = ch;     a.TWFl[(2 * f) * 1024 + s] = cl;
        a.TWFh[(2 * f + 1) * 1024 + s] = sh; a.TWFl[(2 * f + 1) * 1024 + s] = sl;
        a.TWIh[s * 128 + 2 * f] = ch;        a.TWIl[s * 128 + 2 * f] = cl;
        a.TWIh[s * 128 + 2 * f + 1] = sh;    a.TWIl[s * 128 + 2 * f + 1] = sl;
    } else {                               // transpose+split query
        float (*T)[65] = (float(*)[65])smem;
        int t = bid - 256;
        int k0 = (t & 15) * 64, s0 = ((t >> 4) & 15) * 64, b = t >> 8;
        const float* src = a.query + ((size_t)b * 1024 + s0) * 1024 + k0;
        int tr = tid >> 4, tc4 = (tid & 15) * 4;
#pragma unroll
        for (int rs = 0; rs < 4; rs++) {
            int r = rs * 16 + tr;
            float4 v = *(const float4*)&src[(size_t)r * 1024 + tc4];
            T[tc4 + 0][r] = v.x; T[tc4 + 1][r] = v.y;
            T[tc4 + 2][r] = v.z; T[tc4 + 3][r] = v.w;
        }
        __syncthreads();
        unsigned short* dh = a.qTh + ((size_t)b * 1024 + k0) * 1024 + s0;
        unsigned short* dl = a.qTl + ((size_t)b * 1024 + k0) * 1024 + s0;
#pragma unroll
        for (int rs = 0; rs < 4; rs++) {
            int kk = rs * 16 + tr;
            ushort4 hh, ll;
            split2(T[kk][tc4 + 0], hh.x, ll.x);
            split2(T[kk][tc4 + 1], hh.y, ll.y);
            split2(T[kk][tc4 + 2], hh.z, ll.z);
            split2(T[kk][tc4 + 3], hh.w, ll.w);
            *(ushort4*)&dh[(size_t)kk * 1024 + tc4] = hh;
            *(ushort4*)&dl[(size_t)kk * 1024 + tc4] = ll;
        }
        __syncthreads();                   // T reused by next job
    }
}

// ---- 64x64 split-bf16 MFMA NT GEMM tile (R18 body, job-indexed) -------------
template<int KS, int BMODE, bool ASTG, bool BSTG>
__device__ void gemm_tile(int bx, int by, int bzr, int Np, unsigned short* smem,
                          const unsigned short* Ah, const unsigned short* Al,
                          const float* Af32, int lda, long bsA,
                          const unsigned short* Bh, const unsigned short* Bl,
                          const float* Bf32, int ldb, long bsB,
                          float* Cf, int ldc, long bsC,
                          float* Pf, const float* bias, int K)
{
    const int tid = threadIdx.x, lane = tid & 63, w = tid >> 6;
    const int wm = w >> 1, wn = w & 1;
    const int m0 = by * 64, n0 = bx * 64;
    const int la = lane & 15, kg = lane >> 4;
    int bz, ks;
    if constexpr (KS > 1) { bz = bzr / KS; ks = bzr % KS; }
    else                  { bz = bzr; ks = 0; }
    const int Kc = K / KS;

    const unsigned short *pAh = nullptr, *pAl = nullptr, *pBh = nullptr, *pBl = nullptr;
    const float *pA32 = nullptr, *pB32 = nullptr;
    if constexpr (!ASTG) {
        pAh = Ah + (long)bz * bsA + (size_t)(m0 + w * 16 + la) * lda + ks * Kc + kg * 8;
        pAl = Al + (long)bz * bsA + (size_t)(m0 + w * 16 + la) * lda + ks * Kc + kg * 8;
    } else {
        pA32 = Af32 + (long)bz * bsA + (size_t)(m0 + w * 16 + la) * lda + ks * Kc + kg * 8;
    }
    if constexpr (!BSTG) {
        pBh = Bh + (long)bz * bsB + (size_t)(n0 + w * 16 + la) * ldb + ks * Kc + kg * 8;
        pBl = Bl + (long)bz * bsB + (size_t)(n0 + w * 16 + la) * ldb + ks * Kc + kg * 8;
    } else {
        pB32 = Bf32 + (long)bz * bsB + (size_t)(n0 + w * 16 + la) * ldb + ks * Kc + kg * 8;
    }

    __syncthreads();                       // smem handoff from previous job
    if constexpr (!ASTG) {
        gload16(pAh, &smem[w * 512]); gload16(pAl, &smem[2048 + w * 512]);
        pAh += 32; pAl += 32;
    } else {
        float4 a0 = *(const float4*)pA32, a1 = *(const float4*)(pA32 + 4); pA32 += 32;
        splitst(a0, a1, &smem[w * 512 + lane * 8], &smem[2048 + w * 512 + lane * 8]);
    }
    if constexpr (!BSTG) {
        gload16(pBh, &smem[4096 + w * 512]); gload16(pBl, &smem[6144 + w * 512]);
        pBh += 32; pBl += 32;
    } else {
        float4 b0 = *(const float4*)pB32, b1 = *(const float4*)(pB32 + 4); pB32 += 32;
        splitst(b0, b1, &smem[4096 + w * 512 + lane * 8], &smem[6144 + w * 512 + lane * 8]);
    }
    __syncthreads();

    f32x4 acc[2][2] = {};
    int cur = 0;
    for (int kt = 0; kt < Kc; kt += 32) {
        const bool hn = (kt + 32 < Kc);
        float4 na0, na1, nb0, nb1;
        if (hn) {
            int nb = cur ^ 1;
            if constexpr (!ASTG) {
                gload16(pAh, &smem[nb * 8192 + w * 512]);
                gload16(pAl, &smem[nb * 8192 + 2048 + w * 512]);
                pAh += 32; pAl += 32;
            } else {
                na0 = *(const float4*)pA32; na1 = *(const float4*)(pA32 + 4); pA32 += 32;
            }
            if constexpr (!BSTG) {
                gload16(pBh, &smem[nb * 8192 + 4096 + w * 512]);
                gload16(pBl, &smem[nb * 8192 + 6144 + w * 512]);
                pBh += 32; pBl += 32;
            } else {
                nb0 = *(const float4*)pB32; nb1 = *(const float4*)(pB32 + 4); pB32 += 32;
            }
        }
        bf16x8 fah[2], fal[2], fbh[2], fbl[2];
#pragma unroll
        for (int i = 0; i < 2; i++) {
            fah[i] = *reinterpret_cast<const bf16x8*>(&smem[cur * 8192 + (wm * 2 + i) * 512 + lane * 8]);
            fal[i] = *reinterpret_cast<const bf16x8*>(&smem[cur * 8192 + 2048 + (wm * 2 + i) * 512 + lane * 8]);
            fbh[i] = *reinterpret_cast<const bf16x8*>(&smem[cur * 8192 + 4096 + (wn * 2 + i) * 512 + lane * 8]);
            fbl[i] = *reinterpret_cast<const bf16x8*>(&smem[cur * 8192 + 6144 + (wn * 2 + i) * 512 + lane * 8]);
        }
#pragma unroll
        for (int j = 0; j < 2; j++)
#pragma unroll
            for (int i = 0; i < 2; i++) {
                acc[i][j] = __builtin_amdgcn_mfma_f32_16x16x32_bf16(fah[i], fbh[j], acc[i][j], 0, 0, 0);
                acc[i][j] = __builtin_amdgcn_mfma_f32_16x16x32_bf16(fal[i], fbh[j], acc[i][j], 0, 0, 0);
                acc[i][j] = __builtin_amdgcn_mfma_f32_16x16x32_bf16(fah[i], fbl[j], acc[i][j], 0, 0, 0);
            }
        if (hn) {
            int nb = cur ^ 1;
            if constexpr (ASTG)
                splitst(na0, na1, &smem[nb * 8192 + w * 512 + lane * 8],
                                  &smem[nb * 8192 + 2048 + w * 512 + lane * 8]);
            if constexpr (BSTG)
                splitst(nb0, nb1, &smem[nb * 8192 + 4096 + w * 512 + lane * 8],
                                  &smem[nb * 8192 + 6144 + w * 512 + lane * 8]);
        }
        __syncthreads();
        cur ^= 1;
    }

    const int r0_ = (lane >> 4) * 4, cl = lane & 15;
    if constexpr (KS > 1) {
        float* Pb = Pf + (long)bzr * bsC;
#pragma unroll
        for (int i = 0; i < 2; i++)
#pragma unroll
            for (int j = 0; j < 2; j++) {
                int gr0 = m0 + wm * 32 + i * 16 + r0_;
                int gc  = n0 + wn * 32 + j * 16 + cl;
#pragma unroll
                for (int r = 0; r < 4; r++) {
                    int gr = gr0 + r;
                    float v = acc[i][j][r];
                    if (BMODE == 2 && ks == 0 && (gr & 127) == 0)
                        v += 1024.0f * bias[gc];
                    Pb[(long)gr * Np + gc] = v;
                }
            }
    } else {
        float* Cfb = Cf + (long)bz * bsC;
#pragma unroll
        for (int i = 0; i < 2; i++)
#pragma unroll
            for (int j = 0; j < 2; j++) {
                int gr0 = m0 + wm * 32 + i * 16 + r0_;
                int gc  = n0 + wn * 32 + j * 16 + cl;
                float bn = (BMODE == 1) ? bias[gc] : 0.f;
#pragma unroll
                for (int r = 0; r < 4; r++) {
                    int gr = gr0 + r;
                    float v = acc[i][j][r] + bn;
                    if (BMODE == 2 && (gr & 127) == 0) v += 1024.0f * bias[gc];
                    Cfb[(size_t)gr * ldc + gc] = v;
                }
            }
    }
}

// ---- split-K reduce -> bf16 hi/lo (one float4 per thread) -------------------
template<int KS>
__device__ void reduce_dev(int blk, const float* P,
                           unsigned short* Ch, unsigned short* Cl, int mn4bits) {
    int e = blk * 256 + threadIdx.x;
    int bz = e >> mn4bits, rem = e & ((1 << mn4bits) - 1);
    const float4* P4 = (const float4*)P;
    float4 s = P4[((long)(bz * KS) << mn4bits) + rem];
#pragma unroll
    for (int k = 1; k < KS; k++) {
        float4 t = P4[((long)(bz * KS + k) << mn4bits) + rem];
        s.x += t.x; s.y += t.y; s.z += t.z; s.w += t.w;
    }
    long o4 = ((long)bz << mn4bits) + rem;
    ushort4 hh, ll;
    split2(s.x, hh.x, ll.x); split2(s.y, hh.y, ll.y);
    split2(s.z, hh.z, ll.z); split2(s.w, hh.w, ll.w);
    ((ushort4*)Ch)[o4] = hh;
    ((ushort4*)Cl)[o4] = ll;
}

// ---- fused scores + softmax + OVW (job per (b,h)) ---------------------------
__device__ void score_ov_dev(int blk, unsigned short* smem, const MegaArgs& a) {
    float* red = (float*)smem;             // 256 floats
    float* attnL = (float*)smem + 256;     // 64 floats
    const float* P = a.P_B;
    int tid = threadIdx.x;
    int b = blk >> 4, h = blk & 15;
    int f = tid & 63, part = tid >> 6;
    const float* base0 = P + (long)(b * 128 + 2 * f) * 3072 + h * 64 + part * 16;
    float acc = 0.f;
#pragma unroll
    for (int rr = 0; rr < 2; rr++) {
        const float* p0 = base0 + rr * 3072;
        const float* p1 = p0 + PB_STRIDE;
#pragma unroll
        for (int g = 0; g < 4; g++) {
            float4 a0 = *(const float4*)(p0 + g * 4);
            float4 a1 = *(const float4*)(p1 + g * 4);
            float4 k0 = *(const float4*)(p0 + 1024 + g * 4);
            float4 k1 = *(const float4*)(p1 + 1024 + g * 4);
            const float4 wq = *(const float4*)&a.fq[h * 4096 + f * 64 + part * 16 + g * 4];
            const float4 wk = *(const float4*)&a.fk[h * 4096 + f * 64 + part * 16 + g * 4];
            acc += wq.x * wk.x * (a0.x + a1.x) * (k0.x + k1.x)
                 + wq.y * wk.y * (a0.y + a1.y) * (k0.y + k1.y)
                 + wq.z * wk.z * (a0.z + a1.z) * (k0.z + k1.z)
                 + wq.w * wk.w * (a0.w + a1.w) * (k0.w + k1.w);
        }
    }
    red[tid] = acc;
    __syncthreads();
    if (tid < 64) {
        float s = red[tid] + red[tid + 64] + red[tid + 128] + red[tid + 192];
        float mx = s;
        for (int m = 1; m < 64; m <<= 1) mx = fmaxf(mx, __shfl_xor(mx, m));
        mx = fmaxf(mx, 0.0f);                   // padded zero scores join the max
        float e = expf(s - mx);
        float sum = e;
        for (int m = 1; m < 64; m <<= 1) sum += __shfl_xor(sum, m);
        sum += 960.0f * expf(-mx);              // the S-M zero-score entries
        attnL[tid] = e / sum;
    }
    __syncthreads();
#pragma unroll
    for (int it = 0; it < 8; it++) {
        int e = it * 256 + tid;                 // 2048 float4 units
        int f2 = e >> 4, c4 = e & 15;
        int d = c4 * 4;
        const float* p0 = P + (long)(b * 128 + f2) * 3072 + 2048 + h * 64 + d;
        float4 v0 = *(const float4*)p0;
        float4 v1 = *(const float4*)(p0 + PB_STRIDE);
        float av = attnL[f2 >> 1];
        const float4 wvv = *(const float4*)&a.fv[h * 4096 + (f2 >> 1) * 64 + d];
        ushort4 hh, ll;
        split2(av * wvv.x * (v0.x + v1.x), hh.x, ll.x);
        split2(av * wvv.y * (v0.y + v1.y), hh.y, ll.y);
        split2(av * wvv.z * (v0.z + v1.z), hh.z, ll.z);
        split2(av * wvv.w * (v0.w + v1.w), hh.w, ll.w);
        long o4 = ((long)(b * 128 + f2) * 1024 + h * 64 + d) >> 2;
        ((ushort4*)a.OVWh)[o4] = hh;
        ((ushort4*)a.OVWl)[o4] = ll;
    }
    __syncthreads();
}

// ---- the mega-kernel --------------------------------------------------------
__global__ __launch_bounds__(256, 2) void mega(MegaArgs a) {
    __shared__ unsigned short smem[16384];   // 32 KB, reused per stage
    const int blk = blockIdx.x;
    unsigned* cnt = a.bar;
    unsigned* gen = a.bar + 1;

    // stage 0: prep (1280 jobs)
    for (int j = blk; j < 1280; j += NBLK) prep_dev(j, smem, a);
    gbar(cnt, gen);

    // stage A: TWQ-partials (split-K=4), 512 jobs, grid (16,2,16)
    for (int j = blk; j < 512; j += NBLK)
        gemm_tile<4, 0, false, false>(j & 15, (j >> 4) & 1, j >> 5, 1024, smem,
            a.TWFh, a.TWFl, nullptr, 1024, 0, a.qTh, a.qTl, nullptr, 1024, 1048576,
            nullptr, 0, 131072, a.P_A, nullptr, 1024);
    gbar(cnt, gen);

    // reduce A -> TWQ bf16 (131072 float4 over 512x256 threads)
    reduce_dev<4>(blk, a.P_A, a.TWQh, a.TWQl, 15);
    gbar(cnt, gen);

    // stage B: QF-partials (split-K=2, w fp32 staged), 768 jobs, grid (48,8,2)
    for (int j = blk; j < 768; j += NBLK)
        gemm_tile<2, 2, false, true>(j % 48, (j / 48) % 8, j / 384, 3072, smem,
            a.TWQh, a.TWQl, nullptr, 1024, 0, nullptr, nullptr, a.w_qkv, 1024, 0,
            nullptr, 0, PB_STRIDE, a.P_B, a.b_qkv, 1024);
    gbar(cnt, gen);

    // scores + softmax + OVW (64 jobs)
    if (blk < 64) score_ov_dev(blk, smem, a);
    gbar(cnt, gen);

    // stage C: POV-partials (split-K=4, w_out fp32 staged on A), 512 jobs (2,16,16)
    for (int j = blk; j < 512; j += NBLK)
        gemm_tile<4, 0, true, false>(j & 1, (j >> 1) & 15, j >> 5, 128, smem,
            nullptr, nullptr, a.w_out, 1024, 0, a.OVWh, a.OVWl, nullptr, 1024, 131072,
            nullptr, 0, 131072, a.P_C, nullptr, 1024);
    gbar(cnt, gen);

    // reduce C -> POV bf16
    reduce_dev<4>(blk, a.P_C, a.POVh, a.POVl, 15);
    gbar(cnt, gen);

    // stage D: d_out (1024 jobs, grid (16,16,4))
    for (int j = blk; j < 1024; j += NBLK)
        gemm_tile<1, 1, false, false>(j & 15, (j >> 4) & 15, j >> 8, 0, smem,
            a.TWIh, a.TWIl, nullptr, 128, 0, a.POVh, a.POVl, nullptr, 128, 131072,
            a.out, 1024, 1048576, nullptr, a.b_out, 128);
}

extern "C" void kernel_launch(void* const* d_in, const int* in_sizes, int n_in,
                              void* d_out, int out_size, void* d_ws, size_t ws_size,
                              hipStream_t stream) {
    char* W = (char*)d_ws;
    MegaArgs a;
    a.query = (const float*)d_in[0];
    a.w_qkv = (const float*)d_in[1];
    a.b_qkv = (const float*)d_in[2];
    a.w_out = (const float*)d_in[3];
    a.b_out = (const float*)d_in[4];
    a.fq    = (const float*)d_in[5];
    a.fk    = (const float*)d_in[6];
    a.fv    = (const float*)d_in[7];
    a.out   = (float*)d_out;
    a.qTh   = (unsigned short*)(W);                 // [4][1024][1024]
    a.qTl   = (unsigned short*)(W + 8388608);
    a.TWFh  = (unsigned short*)(W + 16777216);      // [128][1024]
    a.TWFl  = (unsigned short*)(W + 17039360);
    a.TWIh  = (unsigned short*)(W + 17301504);      // [1024][128]
    a.TWIl  = (unsigned short*)(W + 17563648);
    a.TWQh  = (unsigned short*)(W + 17825792);      // [512][1024]
    a.TWQl  = (unsigned short*)(W + 18874368);
    a.OVWh  = (unsigned short*)(W + 19922944);      // [4][128][1024]
    a.OVWl  = (unsigned short*)(W + 20971520);
    a.POVh  = (unsigned short*)(W + 22020096);      // [4][1024][128]
    a.POVl  = (unsigned short*)(W + 23068672);
    a.P_A   = (float*)        (W + 24133632);       // [16][2^17]
    a.P_C   = (float*)        (W + 32522240);       // [16][2^17]
    a.P_B   = (float*)        (W + 40910848);       // [2][2^21]
    a.bar   = (unsigned*)     (W + 57688064);       // 2 words

    hipMemsetAsync(a.bar, 0, 2 * sizeof(unsigned), stream);
    mega<<<NBLK, 256, 0, stream>>>(a);
}

// Round 24
// 591.194 us; speedup vs baseline: 1.2685x; 1.2685x over previous
//
#include <hip/hip_runtime.h>
#include <math.h>

// FrequencyAttention mega-kernel (R24 = R23 + fixed barrier): spin with
// RELAXED atomic loads (no per-poll cache invalidate -- R23's 90us/barrier
// bug); exactly one release fence before arrival and one acquire fence after
// exit per block. Stage bodies byte-identical to R19/R23-verified versions.

#define PB_STRIDE 2097152   // floats per P_B slice (2^21)
#define NBLK 512

typedef __bf16 bf16x8 __attribute__((ext_vector_type(8)));
typedef float  f32x4  __attribute__((ext_vector_type(4)));

__device__ __forceinline__ unsigned short f2bf(float x) {
    unsigned u = __builtin_bit_cast(unsigned, x);
    u = (u + 0x7fffu + ((u >> 16) & 1u)) >> 16;   // RTN-even
    return (unsigned short)u;
}
__device__ __forceinline__ float bf2f(unsigned short h) {
    return __builtin_bit_cast(float, ((unsigned)h) << 16);
}
__device__ __forceinline__ void split2(float x, unsigned short& h, unsigned short& l) {
    h = f2bf(x);
    l = f2bf(x - bf2f(h));
}
__device__ __forceinline__ void splitst(const float4& a0, const float4& a1,
                                        unsigned short* dsth, unsigned short* dstl) {
    float v[8] = {a0.x, a0.y, a0.z, a0.w, a1.x, a1.y, a1.z, a1.w};
    bf16x8 hv, lv;
#pragma unroll
    for (int j = 0; j < 8; j++) {
        unsigned short h, l; split2(v[j], h, l);
        hv[j] = __builtin_bit_cast(__bf16, h);
        lv[j] = __builtin_bit_cast(__bf16, l);
    }
    *reinterpret_cast<bf16x8*>(dsth) = hv;
    *reinterpret_cast<bf16x8*>(dstl) = lv;
}
__device__ __forceinline__ void gload16(const void* g, void* l) {
    __builtin_amdgcn_global_load_lds(
        (const __attribute__((address_space(1))) unsigned int*)g,
        (__attribute__((address_space(3))) unsigned int*)l,
        16, 0, 0);
}

// ---- device-scope grid barrier; RELAXED spin (no per-poll invalidate) -------
__device__ __forceinline__ void gbar(unsigned* cnt, unsigned* gen) {
    __syncthreads();
    if (threadIdx.x == 0) {
        __threadfence();   // release: write back this XCD's L2 once
        unsigned g = __hip_atomic_load(gen, __ATOMIC_RELAXED, __HIP_MEMORY_SCOPE_AGENT);
        unsigned a = __hip_atomic_fetch_add(cnt, 1u, __ATOMIC_ACQ_REL, __HIP_MEMORY_SCOPE_AGENT);
        if (a == NBLK - 1u) {
            __hip_atomic_store(cnt, 0u, __ATOMIC_RELAXED, __HIP_MEMORY_SCOPE_AGENT);
            __hip_atomic_store(gen, g + 1u, __ATOMIC_RELEASE, __HIP_MEMORY_SCOPE_AGENT);
        } else {
            while (__hip_atomic_load(gen, __ATOMIC_RELAXED, __HIP_MEMORY_SCOPE_AGENT) == g)
                __builtin_amdgcn_s_sleep(32);
        }
        __threadfence();   // acquire: invalidate stale caches once
    }
    __syncthreads();
}

struct MegaArgs {
    const float *query, *w_qkv, *b_qkv, *w_out, *b_out, *fq, *fk, *fv;
    float* out;
    unsigned short *qTh, *qTl, *TWFh, *TWFl, *TWIh, *TWIl;
    unsigned short *TWQh, *TWQl, *OVWh, *OVWl, *POVh, *POVl;
    float *P_A, *P_C, *P_B;
    unsigned* bar;
};

// ---- prep job (bid in [0,1280)) ---------------------------------------------
__device__ void prep_dev(int bid, unsigned short* smem, const MegaArgs& a) {
    int tid = threadIdx.x;
    if (bid < 256) {                       // twiddles
        int idx = bid * 256 + tid;
        int f = idx >> 10, s = idx & 1023;
        float th = (float)((f * s) & 1023) * (6.283185307179586f / 1024.0f);
        float sn, c;
        sincosf(th, &sn, &c);
        unsigned short ch, cl, sh, sl;
        split2(c, ch, cl); split2(sn, sh, sl);
        a.TWFh[(2 * f) * 1024 + s] = ch;     a.TWFl[(2 * f) * 1024 + s] = cl;
        a.TWFh[(2 * f + 1) * 1024 + s] = sh; a.TWFl[(2 * f + 1) * 1024 + s] = sl;
        a.TWIh[s * 128 + 2 * f] = ch;        a.TWIl[s * 128 + 2 * f] = cl;
        a.TWIh[s * 128 + 2 * f + 1] = sh;    a.TWIl[s * 128 + 2 * f + 1] = sl;
    } else {                               // transpose+split query
        float (*T)[65] = (float(*)[65])smem;
        int t = bid - 256;
        int k0 = (t & 15) * 64, s0 = ((t >> 4) & 15) * 64, b = t >> 8;
        const float* src = a.query + ((size_t)b * 1024 + s0) * 1024 + k0;
        int tr = tid >> 4, tc4 = (tid & 15) * 4;
#pragma unroll
        for (int rs = 0; rs < 4; rs++) {
            int r = rs * 16 + tr;
            float4 v = *(const float4*)&src[(size_t)r * 1024 + tc4];
            T[tc4 + 0][r] = v.x; T[tc4 + 1][r] = v.y;
            T[tc4 + 2][r] = v.z; T[tc4 + 3][r] = v.w;
        }
        __syncthreads();
        unsigned short* dh = a.qTh + ((size_t)b * 1024 + k0) * 1024 + s0;
        unsigned short* dl = a.qTl + ((size_t)b * 1024 + k0) * 1024 + s0;
#pragma unroll
        for (int rs = 0; rs < 4; rs++) {
            int kk = rs * 16 + tr;
            ushort4 hh, ll;
            split2(T[kk][tc4 + 0], hh.x, ll.x);
            split2(T[kk][tc4 + 1], hh.y, ll.y);
            split2(T[kk][tc4 + 2], hh.z, ll.z);
            split2(T[kk][tc4 + 3], hh.w, ll.w);
            *(ushort4*)&dh[(size_t)kk * 1024 + tc4] = hh;
            *(ushort4*)&dl[(size_t)kk * 1024 + tc4] = ll;
        }
        __syncthreads();                   // T reused by next job
    }
}

// ---- 64x64 split-bf16 MFMA NT GEMM tile (R18 body, job-indexed) -------------
template<int KS, int BMODE, bool ASTG, bool BSTG>
__device__ void gemm_tile(int bx, int by, int bzr, int Np, unsigned short* smem,
                          const unsigned short* Ah, const unsigned short* Al,
                          const float* Af32, int lda, long bsA,
                          const unsigned short* Bh, const unsigned short* Bl,
                          const float* Bf32, int ldb, long bsB,
                          float* Cf, int ldc, long bsC,
                          float* Pf, const float* bias, int K)
{
    const int tid = threadIdx.x, lane = tid & 63, w = tid >> 6;
    const int wm = w >> 1, wn = w & 1;
    const int m0 = by * 64, n0 = bx * 64;
    const int la = lane & 15, kg = lane >> 4;
    int bz, ks;
    if constexpr (KS > 1) { bz = bzr / KS; ks = bzr % KS; }
    else                  { bz = bzr; ks = 0; }
    const int Kc = K / KS;

    const unsigned short *pAh = nullptr, *pAl = nullptr, *pBh = nullptr, *pBl = nullptr;
    const float *pA32 = nullptr, *pB32 = nullptr;
    if constexpr (!ASTG) {
        pAh = Ah + (long)bz * bsA + (size_t)(m0 + w * 16 + la) * lda + ks * Kc + kg * 8;
        pAl = Al + (long)bz * bsA + (size_t)(m0 + w * 16 + la) * lda + ks * Kc + kg * 8;
    } else {
        pA32 = Af32 + (long)bz * bsA + (size_t)(m0 + w * 16 + la) * lda + ks * Kc + kg * 8;
    }
    if constexpr (!BSTG) {
        pBh = Bh + (long)bz * bsB + (size_t)(n0 + w * 16 + la) * ldb + ks * Kc + kg * 8;
        pBl = Bl + (long)bz * bsB + (size_t)(n0 + w * 16 + la) * ldb + ks * Kc + kg * 8;
    } else {
        pB32 = Bf32 + (long)bz * bsB + (size_t)(n0 + w * 16 + la) * ldb + ks * Kc + kg * 8;
    }

    __syncthreads();                       // smem handoff from previous job
    if constexpr (!ASTG) {
        gload16(pAh, &smem[w * 512]); gload16(pAl, &smem[2048 + w * 512]);
        pAh += 32; pAl += 32;
    } else {
        float4 a0 = *(const float4*)pA32, a1 = *(const float4*)(pA32 + 4); pA32 += 32;
        splitst(a0, a1, &smem[w * 512 + lane * 8], &smem[2048 + w * 512 + lane * 8]);
    }
    if constexpr (!BSTG) {
        gload16(pBh, &smem[4096 + w * 512]); gload16(pBl, &smem[6144 + w * 512]);
        pBh += 32; pBl += 32;
    } else {
        float4 b0 = *(const float4*)pB32, b1 = *(const float4*)(pB32 + 4); pB32 += 32;
        splitst(b0, b1, &smem[4096 + w * 512 + lane * 8], &smem[6144 + w * 512 + lane * 8]);
    }
    __syncthreads();

    f32x4 acc[2][2] = {};
    int cur = 0;
    for (int kt = 0; kt < Kc; kt += 32) {
        const bool hn = (kt + 32 < Kc);
        float4 na0, na1, nb0, nb1;
        if (hn) {
            int nb = cur ^ 1;
            if constexpr (!ASTG) {
                gload16(pAh, &smem[nb * 8192 + w * 512]);
                gload16(pAl, &smem[nb * 8192 + 2048 + w * 512]);
                pAh += 32; pAl += 32;
            } else {
                na0 = *(const float4*)pA32; na1 = *(const float4*)(pA32 + 4); pA32 += 32;
            }
            if constexpr (!BSTG) {
                gload16(pBh, &smem[nb * 8192 + 4096 + w * 512]);
                gload16(pBl, &smem[nb * 8192 + 6144 + w * 512]);
                pBh += 32; pBl += 32;
            } else {
                nb0 = *(const float4*)pB32; nb1 = *(const float4*)(pB32 + 4); pB32 += 32;
            }
        }
        bf16x8 fah[2], fal[2], fbh[2], fbl[2];
#pragma unroll
        for (int i = 0; i < 2; i++) {
            fah[i] = *reinterpret_cast<const bf16x8*>(&smem[cur * 8192 + (wm * 2 + i) * 512 + lane * 8]);
            fal[i] = *reinterpret_cast<const bf16x8*>(&smem[cur * 8192 + 2048 + (wm * 2 + i) * 512 + lane * 8]);
            fbh[i] = *reinterpret_cast<const bf16x8*>(&smem[cur * 8192 + 4096 + (wn * 2 + i) * 512 + lane * 8]);
            fbl[i] = *reinterpret_cast<const bf16x8*>(&smem[cur * 8192 + 6144 + (wn * 2 + i) * 512 + lane * 8]);
        }
#pragma unroll
        for (int j = 0; j < 2; j++)
#pragma unroll
            for (int i = 0; i < 2; i++) {
                acc[i][j] = __builtin_amdgcn_mfma_f32_16x16x32_bf16(fah[i], fbh[j], acc[i][j], 0, 0, 0);
                acc[i][j] = __builtin_amdgcn_mfma_f32_16x16x32_bf16(fal[i], fbh[j], acc[i][j], 0, 0, 0);
                acc[i][j] = __builtin_amdgcn_mfma_f32_16x16x32_bf16(fah[i], fbl[j], acc[i][j], 0, 0, 0);
            }
        if (hn) {
            int nb = cur ^ 1;
            if constexpr (ASTG)
                splitst(na0, na1, &smem[nb * 8192 + w * 512 + lane * 8],
                                  &smem[nb * 8192 + 2048 + w * 512 + lane * 8]);
            if constexpr (BSTG)
                splitst(nb0, nb1, &smem[nb * 8192 + 4096 + w * 512 + lane * 8],
                                  &smem[nb * 8192 + 6144 + w * 512 + lane * 8]);
        }
        __syncthreads();
        cur ^= 1;
    }

    const int r0_ = (lane >> 4) * 4, cl = lane & 15;
    if constexpr (KS > 1) {
        float* Pb = Pf + (long)bzr * bsC;
#pragma unroll
        for (int i = 0; i < 2; i++)
#pragma unroll
            for (int j = 0; j < 2; j++) {
                int gr0 = m0 + wm * 32 + i * 16 + r0_;
                int gc  = n0 + wn * 32 + j * 16 + cl;
#pragma unroll
                for (int r = 0; r < 4; r++) {
                    int gr = gr0 + r;
                    float v = acc[i][j][r];
                    if (BMODE == 2 && ks == 0 && (gr & 127) == 0)
                        v += 1024.0f * bias[gc];
                    Pb[(long)gr * Np + gc] = v;
                }
            }
    } else {
        float* Cfb = Cf + (long)bz * bsC;
#pragma unroll
        for (int i = 0; i < 2; i++)
#pragma unroll
            for (int j = 0; j < 2; j++) {
                int gr0 = m0 + wm * 32 + i * 16 + r0_;
                int gc  = n0 + wn * 32 + j * 16 + cl;
                float bn = (BMODE == 1) ? bias[gc] : 0.f;
#pragma unroll
                for (int r = 0; r < 4; r++) {
                    int gr = gr0 + r;
                    float v = acc[i][j][r] + bn;
                    if (BMODE == 2 && (gr & 127) == 0) v += 1024.0f * bias[gc];
                    Cfb[(size_t)gr * ldc + gc] = v;
                }
            }
    }
}

// ---- split-K reduce -> bf16 hi/lo (one float4 per thread) -------------------
template<int KS>
__device__ void reduce_dev(int blk, const float* P,
                           unsigned short* Ch, unsigned short* Cl, int mn4bits) {
    int e = blk * 256 + threadIdx.x;
    int bz = e >> mn4bits, rem = e & ((1 << mn4bits) - 1);
    const float4* P4 = (const float4*)P;
    float4 s = P4[((long)(bz * KS) << mn4bits) + rem];
#pragma unroll
    for (int k = 1; k < KS; k++) {
        float4 t = P4[((long)(bz * KS + k) << mn4bits) + rem];
        s.x += t.x; s.y += t.y; s.z += t.z; s.w += t.w;
    }
    long o4 = ((long)bz << mn4bits) + rem;
    ushort4 hh, ll;
    split2(s.x, hh.x, ll.x); split2(s.y, hh.y, ll.y);
    split2(s.z, hh.z, ll.z); split2(s.w, hh.w, ll.w);
    ((ushort4*)Ch)[o4] = hh;
    ((ushort4*)Cl)[o4] = ll;
}

// ---- fused scores + softmax + OVW (job per (b,h)) ---------------------------
__device__ void score_ov_dev(int blk, unsigned short* smem, const MegaArgs& a) {
    float* red = (float*)smem;             // 256 floats
    float* attnL = (float*)smem + 256;     // 64 floats
    const float* P = a.P_B;
    int tid = threadIdx.x;
    int b = blk >> 4, h = blk & 15;
    int f = tid & 63, part = tid >> 6;
    const float* base0 = P + (long)(b * 128 + 2 * f) * 3072 + h * 64 + part * 16;
    float acc = 0.f;
#pragma unroll
    for (int rr = 0; rr < 2; rr++) {
        const float* p0 = base0 + rr * 3072;
        const float* p1 = p0 + PB_STRIDE;
#pragma unroll
        for (int g = 0; g < 4; g++) {
            float4 a0 = *(const float4*)(p0 + g * 4);
            float4 a1 = *(const float4*)(p1 + g * 4);
            float4 k0 = *(const float4*)(p0 + 1024 + g * 4);
            float4 k1 = *(const float4*)(p1 + 1024 + g * 4);
            const float4 wq = *(const float4*)&a.fq[h * 4096 + f * 64 + part * 16 + g * 4];
            const float4 wk = *(const float4*)&a.fk[h * 4096 + f * 64 + part * 16 + g * 4];
            acc += wq.x * wk.x * (a0.x + a1.x) * (k0.x + k1.x)
                 + wq.y * wk.y * (a0.y + a1.y) * (k0.y + k1.y)
                 + wq.z * wk.z * (a0.z + a1.z) * (k0.z + k1.z)
                 + wq.w * wk.w * (a0.w + a1.w) * (k0.w + k1.w);
        }
    }
    red[tid] = acc;
    __syncthreads();
    if (tid < 64) {
        float s = red[tid] + red[tid + 64] + red[tid + 128] + red[tid + 192];
        float mx = s;
        for (int m = 1; m < 64; m <<= 1) mx = fmaxf(mx, __shfl_xor(mx, m));
        mx = fmaxf(mx, 0.0f);                   // padded zero scores join the max
        float e = expf(s - mx);
        float sum = e;
        for (int m = 1; m < 64; m <<= 1) sum += __shfl_xor(sum, m);
        sum += 960.0f * expf(-mx);              // the S-M zero-score entries
        attnL[tid] = e / sum;
    }
    __syncthreads();
#pragma unroll
    for (int it = 0; it < 8; it++) {
        int e = it * 256 + tid;                 // 2048 float4 units
        int f2 = e >> 4, c4 = e & 15;
        int d = c4 * 4;
        const float* p0 = P + (long)(b * 128 + f2) * 3072 + 2048 + h * 64 + d;
        float4 v0 = *(const float4*)p0;
        float4 v1 = *(const float4*)(p0 + PB_STRIDE);
        float av = attnL[f2 >> 1];
        const float4 wvv = *(const float4*)&a.fv[h * 4096 + (f2 >> 1) * 64 + d];
        ushort4 hh, ll;
        split2(av * wvv.x * (v0.x + v1.x), hh.x, ll.x);
        split2(av * wvv.y * (v0.y + v1.y), hh.y, ll.y);
        split2(av * wvv.z * (v0.z + v1.z), hh.z, ll.z);
        split2(av * wvv.w * (v0.w + v1.w), hh.w, ll.w);
        long o4 = ((long)(b * 128 + f2) * 1024 + h * 64 + d) >> 2;
        ((ushort4*)a.OVWh)[o4] = hh;
        ((ushort4*)a.OVWl)[o4] = ll;
    }
    __syncthreads();
}

// ---- the mega-kernel --------------------------------------------------------
__global__ __launch_bounds__(256, 2) void mega(MegaArgs a) {
    __shared__ unsigned short smem[16384];   // 32 KB, reused per stage
    const int blk = blockIdx.x;
    unsigned* cnt = a.bar;
    unsigned* gen = a.bar + 1;

    // stage 0: prep (1280 jobs)
    for (int j = blk; j < 1280; j += NBLK) prep_dev(j, smem, a);
    gbar(cnt, gen);

    // stage A: TWQ-partials (split-K=4), 512 jobs, grid (16,2,16)
    for (int j = blk; j < 512; j += NBLK)
        gemm_tile<4, 0, false, false>(j & 15, (j >> 4) & 1, j >> 5, 1024, smem,
            a.TWFh, a.TWFl, nullptr, 1024, 0, a.qTh, a.qTl, nullptr, 1024, 1048576,
            nullptr, 0, 131072, a.P_A, nullptr, 1024);
    gbar(cnt, gen);

    // reduce A -> TWQ bf16 (131072 float4 over 512x256 threads)
    reduce_dev<4>(blk, a.P_A, a.TWQh, a.TWQl, 15);
    gbar(cnt, gen);

    // stage B: QF-partials (split-K=2, w fp32 staged), 768 jobs, grid (48,8,2)
    for (int j = blk; j < 768; j += NBLK)
        gemm_tile<2, 2, false, true>(j % 48, (j / 48) % 8, j / 384, 3072, smem,
            a.TWQh, a.TWQl, nullptr, 1024, 0, nullptr, nullptr, a.w_qkv, 1024, 0,
            nullptr, 0, PB_STRIDE, a.P_B, a.b_qkv, 1024);
    gbar(cnt, gen);

    // scores + softmax + OVW (64 jobs)
    if (blk < 64) score_ov_dev(blk, smem, a);
    gbar(cnt, gen);

    // stage C: POV-partials (split-K=4, w_out fp32 staged on A), 512 jobs (2,16,16)
    for (int j = blk; j < 512; j += NBLK)
        gemm_tile<4, 0, true, false>(j & 1, (j >> 1) & 15, j >> 5, 128, smem,
            nullptr, nullptr, a.w_out, 1024, 0, a.OVWh, a.OVWl, nullptr, 1024, 131072,
            nullptr, 0, 131072, a.P_C, nullptr, 1024);
    gbar(cnt, gen);

    // reduce C -> POV bf16
    reduce_dev<4>(blk, a.P_C, a.POVh, a.POVl, 15);
    gbar(cnt, gen);

    // stage D: d_out (1024 jobs, grid (16,16,4))
    for (int j = blk; j < 1024; j += NBLK)
        gemm_tile<1, 1, false, false>(j & 15, (j >> 4) & 15, j >> 8, 0, smem,
            a.TWIh, a.TWIl, nullptr, 128, 0, a.POVh, a.POVl, nullptr, 128, 131072,
            a.out, 1024, 1048576, nullptr, a.b_out, 128);
}

extern "C" void kernel_launch(void* const* d_in, const int* in_sizes, int n_in,
                              void* d_out, int out_size, void* d_ws, size_t ws_size,
                              hipStream_t stream) {
    char* W = (char*)d_ws;
    MegaArgs a;
    a.query = (const float*)d_in[0];
    a.w_qkv = (const float*)d_in[1];
    a.b_qkv = (const float*)d_in[2];
    a.w_out = (const float*)d_in[3];
    a.b_out = (const float*)d_in[4];
    a.fq    = (const float*)d_in[5];
    a.fk    = (const float*)d_in[6];
    a.fv    = (const float*)d_in[7];
    a.out   = (float*)d_out;
    a.qTh   = (unsigned short*)(W);                 // [4][1024][1024]
    a.qTl   = (unsigned short*)(W + 8388608);
    a.TWFh  = (unsigned short*)(W + 16777216);      // [128][1024]
    a.TWFl  = (unsigned short*)(W + 17039360);
    a.TWIh  = (unsigned short*)(W + 17301504);      // [1024][128]
    a.TWIl  = (unsigned short*)(W + 17563648);
    a.TWQh  = (unsigned short*)(W + 17825792);      // [512][1024]
    a.TWQl  = (unsigned short*)(W + 18874368);
    a.OVWh  = (unsigned short*)(W + 19922944);      // [4][128][1024]
    a.OVWl  = (unsigned short*)(W + 20971520);
    a.POVh  = (unsigned short*)(W + 22020096);      // [4][1024][128]
    a.POVl  = (unsigned short*)(W + 23068672);
    a.P_A   = (float*)        (W + 24133632);       // [16][2^17]
    a.P_C   = (float*)        (W + 32522240);       // [16][2^17]
    a.P_B   = (float*)        (W + 40910848);       // [2][2^21]
    a.bar   = (unsigned*)     (W + 57688064);       // 2 words

    hipMemsetAsync(a.bar, 0, 2 * sizeof(unsigned), stream);
    mega<<<NBLK, 256, 0, stream>>>(a);
}